// Round 3
// baseline (918.656 us; speedup 1.0000x reference)
//
#include <hip/hip_runtime.h>

// MoE: T=8192 tokens, D=1024, F=4096, E=8, top-2.
// Pipeline: cast/transpose weights to bf16 -> gate -> scatter to expert lists
// -> grouped GEMM1 (x@w1+b1, gelu) -> H -> grouped GEMM2 (H@w2+b2, *gate_wt,
// atomicAdd into out).
// R2: pipelined K-loop (double LDS buffer, raw s_barrier, vmcnt(4), prefetch
// distance 2). R3 fix: R2 raced — the read-done barrier lacked lgkmcnt(0), so
// waves crossed it with ds_reads still queued in the DS pipe while the next
// tile's lds-DMA (VMEM pipe, unordered vs DS) overwrote the buffer. Drain
// lgkmcnt (NOT vmcnt) before the second barrier.

#define T_TOK 8192
#define D_DIM 1024
#define F_DIM 4096
#define E_NUM 8
#define BM 128
#define BN 128
#define BK 32
#define NK1 (D_DIM / BK)
#define NK2 (F_DIM / BK)
#define MAX_TILES (T_TOK * 2 / BM + E_NUM)  // 136 worst case

typedef float f32x4 __attribute__((ext_vector_type(4)));
typedef short bf16x8 __attribute__((ext_vector_type(8)));

__device__ __forceinline__ unsigned short f2bf(float f) {
  union { float f; unsigned u; } v; v.f = f;
  unsigned r = v.u + 0x7FFFu + ((v.u >> 16) & 1u);  // RNE
  return (unsigned short)(r >> 16);
}

__device__ __forceinline__ void async_cp16(const unsigned short* g, unsigned short* l) {
  // 16B-wide global->LDS DMA. LDS dest is wave-uniform base + lane*16.
  __builtin_amdgcn_global_load_lds((__attribute__((address_space(1))) void*)g,
                                   (__attribute__((address_space(3))) void*)l,
                                   16, 0, 0);
}

#define WAIT_VM4 asm volatile("s_waitcnt vmcnt(4)" ::: "memory")
#define WAIT_LGKM0 asm volatile("s_waitcnt lgkmcnt(0)" ::: "memory")
#define RAW_BARRIER asm volatile("s_barrier" ::: "memory")

// ---------------- small prep kernels ----------------

__global__ void cast_x_kernel(const float* __restrict__ src,
                              unsigned short* __restrict__ dst, int n4) {
  int i = blockIdx.x * blockDim.x + threadIdx.x;
  if (i >= n4) return;
  float4 v = ((const float4*)src)[i];
  ushort4 o;
  o.x = f2bf(v.x); o.y = f2bf(v.y); o.z = f2bf(v.z); o.w = f2bf(v.w);
  ((ushort4*)dst)[i] = o;
}

// src fp32 [R][C] row-major (per expert) -> dst bf16 [C][R]; float4 loads,
// ushort4 stores.
__global__ __launch_bounds__(256) void transpose_cast_kernel(
    const float* __restrict__ src, unsigned short* __restrict__ dst,
    int R, int C) {
  __shared__ float tile[64][68];
  int e = blockIdx.z;
  src += (size_t)e * R * C;
  dst += (size_t)e * R * C;
  int c0 = blockIdx.x * 64;
  int r0 = blockIdx.y * 64;
  int t = threadIdx.x;
  int cl = (t & 15) * 4, rl = t >> 4;  // 16 rows/pass
#pragma unroll
  for (int i = 0; i < 4; ++i) {
    int r = rl + i * 16;
    float4 v = *(const float4*)(src + (size_t)(r0 + r) * C + c0 + cl);
    *(float4*)&tile[r][cl] = v;
  }
  __syncthreads();
  int rl2 = (t & 15) * 4, cl2 = t >> 4;
#pragma unroll
  for (int i = 0; i < 4; ++i) {
    int c = cl2 + i * 16;
    ushort4 o;
    o.x = f2bf(tile[rl2 + 0][c]);
    o.y = f2bf(tile[rl2 + 1][c]);
    o.z = f2bf(tile[rl2 + 2][c]);
    o.w = f2bf(tile[rl2 + 3][c]);
    *(ushort4*)(dst + (size_t)(c0 + c) * R + r0 + rl2) = o;
  }
}

// one wave per token: logits = x[t] . gate_w[:,e], fp32; top-2 + softmax
__global__ __launch_bounds__(256) void gate_kernel(
    const float* __restrict__ x, const float* __restrict__ gw,
    float* __restrict__ topk_w, int* __restrict__ topk_e) {
  int t = (blockIdx.x * 256 + threadIdx.x) >> 6;
  int lane = threadIdx.x & 63;
  const float* xr = x + (size_t)t * D_DIM;
  float acc[8];
#pragma unroll
  for (int e = 0; e < 8; ++e) acc[e] = 0.f;
  for (int j = 0; j < D_DIM / 64; ++j) {
    int d = lane + 64 * j;
    float xv = xr[d];
    float4 g0 = ((const float4*)(gw + (size_t)d * 8))[0];
    float4 g1 = ((const float4*)(gw + (size_t)d * 8))[1];
    acc[0] += xv * g0.x; acc[1] += xv * g0.y;
    acc[2] += xv * g0.z; acc[3] += xv * g0.w;
    acc[4] += xv * g1.x; acc[5] += xv * g1.y;
    acc[6] += xv * g1.z; acc[7] += xv * g1.w;
  }
#pragma unroll
  for (int off = 32; off > 0; off >>= 1) {
#pragma unroll
    for (int e = 0; e < 8; ++e) acc[e] += __shfl_xor(acc[e], off);
  }
  if (lane == 0) {
    int e0 = 0; float v0 = acc[0];
#pragma unroll
    for (int e = 1; e < 8; ++e)
      if (acc[e] > v0) { v0 = acc[e]; e0 = e; }  // strict >: lowest index on tie
    int e1 = -1; float v1 = -1e30f;
#pragma unroll
    for (int e = 0; e < 8; ++e)
      if (e != e0 && acc[e] > v1) { v1 = acc[e]; e1 = e; }
    float ex = expf(v1 - v0);
    float inv = 1.f / (1.f + ex);
    topk_w[2 * t] = inv;
    topk_w[2 * t + 1] = ex * inv;
    topk_e[2 * t] = e0;
    topk_e[2 * t + 1] = e1;
  }
}

__global__ void scatter_kernel(const int* __restrict__ topk_e,
                               int* __restrict__ cnt, int* __restrict__ assign) {
  int idx = blockIdx.x * blockDim.x + threadIdx.x;  // (t,k) pair id = t*2+k
  int e = topk_e[idx];
  int pos = atomicAdd(&cnt[e], 1);
  assign[e * T_TOK + pos] = idx;
}

__global__ void tiles_kernel(const int* __restrict__ cnt,
                             int* __restrict__ ndesc, int4* __restrict__ desc) {
  if (threadIdx.x != 0) return;
  int nt = 0, hb = 0;
  for (int e = 0; e < E_NUM; ++e) {
    int c = cnt[e];
    for (int s = 0; s < c; s += BM) {
      int4 d;
      d.x = e; d.y = s; d.z = hb;
      d.w = (c - s < BM) ? (c - s) : BM;
      desc[nt++] = d;
    }
    hb += c;
  }
  *ndesc = nt;
}

// ---------------- grouped GEMMs (pipelined) ----------------
// 128x128 tile, BK=32, 4 waves each 64x64, 16x mfma_f32_16x16x32_bf16 per
// K-step. LDS chunk swizzle (rotate 16B chunk by row) cuts frag-read bank
// conflicts (lds-DMA forbids padding). Double-buffered, prefetch distance 2,
// vmcnt(4) waits only on the tile being consumed. Step structure:
//   vmcnt(4) ; barrier ; ds_read frags ; lgkmcnt(0) ; barrier ; issue k+2 ; MFMA
// The lgkmcnt(0) before barrier-2 is REQUIRED: DS-pipe reads are unordered
// vs the VMEM-pipe lds-DMA that overwrites the buffer after the barrier.

// GEMM1: H[slot][f] = gelu(x[tok] @ w1[e] + b1[e]);  A gathered via assign.
__global__ __launch_bounds__(256) void gemm1_kernel(
    const unsigned short* __restrict__ xb, const unsigned short* __restrict__ w1t,
    const float* __restrict__ b1, const int* __restrict__ assign,
    const int* __restrict__ ndesc, const int4* __restrict__ desc,
    unsigned short* __restrict__ H) {
  int tileid = blockIdx.y;
  if (tileid >= *ndesc) return;
  int4 dc = desc[tileid];
  int e = dc.x, start = dc.y, hbase = dc.z, mcnt = dc.w;
  int n0 = blockIdx.x * BN;  // f-offset

  __shared__ __attribute__((aligned(16))) unsigned short As[2][BM * BK];
  __shared__ __attribute__((aligned(16))) unsigned short Bs[2][BN * BK];

  int tid = threadIdx.x, lane = tid & 63, wv = tid >> 6;

  const unsigned short* gA[2]; const unsigned short* gB[2];
  int loff[2];
#pragma unroll
  for (int s = 0; s < 2; ++s) {
    int L = tid + s * 256;           // 16B chunk id
    int row = L >> 2, cc = L & 3;
    int g = (cc - row) & 3;          // swizzle: LDS[row][cc] = glob[row][(cc-row)&3]
    int rowc = row < mcnt ? row : (mcnt - 1);
    int a = assign[e * T_TOK + start + rowc];
    gA[s] = xb + (size_t)(a >> 1) * D_DIM + g * 8;
    gB[s] = w1t + (size_t)(e * F_DIM + n0 + row) * D_DIM + g * 8;
    loff[s] = (s * 256 + wv * 64) * 8;  // wave-uniform LDS chunk base
  }

  int kc16 = lane >> 4, r16 = lane & 15;
  int m_off = (wv & 1) * 64, n_off = (wv >> 1) * 64;
  int aoff[4], boff[4];
#pragma unroll
  for (int i = 0; i < 4; ++i) {
    int ra = m_off + i * 16 + r16;
    aoff[i] = ra * 32 + ((kc16 + ra) & 3) * 8;
    int rb = n_off + i * 16 + r16;
    boff[i] = rb * 32 + ((kc16 + rb) & 3) * 8;
  }

  f32x4 acc[4][4];
#pragma unroll
  for (int i = 0; i < 4; ++i)
#pragma unroll
    for (int j = 0; j < 4; ++j) acc[i][j] = (f32x4){0.f, 0.f, 0.f, 0.f};

  auto issue = [&](int t, int b) {
    int kc = (t < NK1 ? t : NK1 - 1) * BK;
#pragma unroll
    for (int s = 0; s < 2; ++s) {
      async_cp16(gA[s] + kc, &As[b][loff[s]]);
      async_cp16(gB[s] + kc, &Bs[b][loff[s]]);
    }
  };
  auto step = [&](int kt, int b) {
    WAIT_VM4;       // tile kt's 4 DMAs done; tile kt+1's stay in flight
    RAW_BARRIER;    // all waves have tile kt in LDS
    bf16x8 af[4], bfr[4];
#pragma unroll
    for (int i = 0; i < 4; ++i) af[i] = *(const bf16x8*)(&As[b][0] + aoff[i]);
#pragma unroll
    for (int i = 0; i < 4; ++i) bfr[i] = *(const bf16x8*)(&Bs[b][0] + boff[i]);
    WAIT_LGKM0;     // DS queue drained: frags are in registers
    RAW_BARRIER;    // all waves done reading buffer b -> safe to overwrite
    issue(kt + 2, b);
#pragma unroll
    for (int i = 0; i < 4; ++i)
#pragma unroll
      for (int j = 0; j < 4; ++j)
        acc[i][j] = __builtin_amdgcn_mfma_f32_16x16x32_bf16(af[i], bfr[j], acc[i][j], 0, 0, 0);
  };

  issue(0, 0);
  issue(1, 1);
  for (int kt = 0; kt < NK1; kt += 2) { step(kt, 0); step(kt + 1, 1); }

  // epilogue: C/D layout col=lane&15, row=(lane>>4)*4+reg
  int col = lane & 15, rbase = (lane >> 4) * 4;
  float bias[4];
#pragma unroll
  for (int j = 0; j < 4; ++j) bias[j] = b1[e * F_DIM + n0 + n_off + j * 16 + col];
#pragma unroll
  for (int i = 0; i < 4; ++i) {
#pragma unroll
    for (int rg = 0; rg < 4; ++rg) {
      int r = m_off + i * 16 + rbase + rg;
      if (r < mcnt) {
        unsigned short* hrow = H + (size_t)(hbase + start + r) * F_DIM + n0 + n_off + col;
#pragma unroll
        for (int j = 0; j < 4; ++j) {
          float v = acc[i][j][rg] + bias[j];
          v = 0.5f * v * (1.0f + erff(v * 0.70710678118654752f));  // exact gelu
          hrow[j * 16] = f2bf(v);
        }
      }
    }
  }
}

// GEMM2: out[tok] += wt * (H[slot] @ w2[e] + b2[e])
__global__ __launch_bounds__(256) void gemm2_kernel(
    const unsigned short* __restrict__ H, const unsigned short* __restrict__ w2t,
    const float* __restrict__ b2, const int* __restrict__ assign,
    const float* __restrict__ topk_w,
    const int* __restrict__ ndesc, const int4* __restrict__ desc,
    float* __restrict__ out) {
  int tileid = blockIdx.y;
  if (tileid >= *ndesc) return;
  int4 dc = desc[tileid];
  int e = dc.x, start = dc.y, hbase = dc.z, mcnt = dc.w;
  int n0 = blockIdx.x * BN;  // d-offset

  __shared__ __attribute__((aligned(16))) unsigned short As[2][BM * BK];
  __shared__ __attribute__((aligned(16))) unsigned short Bs[2][BN * BK];

  int tid = threadIdx.x, lane = tid & 63, wv = tid >> 6;

  const unsigned short* gA[2]; const unsigned short* gB[2];
  int loff[2];
#pragma unroll
  for (int s = 0; s < 2; ++s) {
    int L = tid + s * 256;
    int row = L >> 2, cc = L & 3;
    int g = (cc - row) & 3;
    int rowc = row < mcnt ? row : (mcnt - 1);
    gA[s] = H + (size_t)(hbase + start + rowc) * F_DIM + g * 8;
    gB[s] = w2t + (size_t)(e * D_DIM + n0 + row) * F_DIM + g * 8;
    loff[s] = (s * 256 + wv * 64) * 8;
  }

  int kc16 = lane >> 4, r16 = lane & 15;
  int m_off = (wv & 1) * 64, n_off = (wv >> 1) * 64;
  int aoff[4], boff[4];
#pragma unroll
  for (int i = 0; i < 4; ++i) {
    int ra = m_off + i * 16 + r16;
    aoff[i] = ra * 32 + ((kc16 + ra) & 3) * 8;
    int rb = n_off + i * 16 + r16;
    boff[i] = rb * 32 + ((kc16 + rb) & 3) * 8;
  }

  f32x4 acc[4][4];
#pragma unroll
  for (int i = 0; i < 4; ++i)
#pragma unroll
    for (int j = 0; j < 4; ++j) acc[i][j] = (f32x4){0.f, 0.f, 0.f, 0.f};

  auto issue = [&](int t, int b) {
    int kc = (t < NK2 ? t : NK2 - 1) * BK;
#pragma unroll
    for (int s = 0; s < 2; ++s) {
      async_cp16(gA[s] + kc, &As[b][loff[s]]);
      async_cp16(gB[s] + kc, &Bs[b][loff[s]]);
    }
  };
  auto step = [&](int kt, int b) {
    WAIT_VM4;
    RAW_BARRIER;
    bf16x8 af[4], bfr[4];
#pragma unroll
    for (int i = 0; i < 4; ++i) af[i] = *(const bf16x8*)(&As[b][0] + aoff[i]);
#pragma unroll
    for (int i = 0; i < 4; ++i) bfr[i] = *(const bf16x8*)(&Bs[b][0] + boff[i]);
    WAIT_LGKM0;
    RAW_BARRIER;
    issue(kt + 2, b);
#pragma unroll
    for (int i = 0; i < 4; ++i)
#pragma unroll
      for (int j = 0; j < 4; ++j)
        acc[i][j] = __builtin_amdgcn_mfma_f32_16x16x32_bf16(af[i], bfr[j], acc[i][j], 0, 0, 0);
  };

  issue(0, 0);
  issue(1, 1);
  for (int kt = 0; kt < NK2; kt += 2) { step(kt, 0); step(kt + 1, 1); }

  int col = lane & 15, rbase = (lane >> 4) * 4;
  float bias[4];
#pragma unroll
  for (int j = 0; j < 4; ++j) bias[j] = b2[e * D_DIM + n0 + n_off + j * 16 + col];
#pragma unroll
  for (int i = 0; i < 4; ++i) {
#pragma unroll
    for (int rg = 0; rg < 4; ++rg) {
      int r = m_off + i * 16 + rbase + rg;
      if (r < mcnt) {
        int a = assign[e * T_TOK + start + r];
        float wt = topk_w[a];
        float* orow = out + (size_t)(a >> 1) * D_DIM + n0 + n_off + col;
#pragma unroll
        for (int j = 0; j < 4; ++j) {
          float v = acc[i][j][rg] + bias[j];
          atomicAdd(orow + j * 16, wt * v);  // 2 contenders/address
        }
      }
    }
  }
}

// ---------------- launcher ----------------

extern "C" void kernel_launch(void* const* d_in, const int* in_sizes, int n_in,
                              void* d_out, int out_size, void* d_ws, size_t ws_size,
                              hipStream_t stream) {
  const float* x      = (const float*)d_in[0];
  const float* gate_w = (const float*)d_in[1];
  const float* w1     = (const float*)d_in[2];
  const float* b1     = (const float*)d_in[3];
  const float* w2     = (const float*)d_in[4];
  const float* b2     = (const float*)d_in[5];
  float* out = (float*)d_out;

  char* ws = (char*)d_ws;
  size_t off = 0;
  auto alloc = [&](size_t bytes) {
    char* p = ws + off;
    off = (off + bytes + 255) & ~(size_t)255;
    return p;
  };
  unsigned short* xb   = (unsigned short*)alloc((size_t)T_TOK * D_DIM * 2);
  unsigned short* w1t  = (unsigned short*)alloc((size_t)E_NUM * D_DIM * F_DIM * 2);
  unsigned short* w2t  = (unsigned short*)alloc((size_t)E_NUM * D_DIM * F_DIM * 2);
  unsigned short* Hbuf = (unsigned short*)alloc((size_t)2 * T_TOK * F_DIM * 2);
  float* topk_w = (float*)alloc((size_t)2 * T_TOK * 4);
  int* topk_e   = (int*)alloc((size_t)2 * T_TOK * 4);
  int* assign   = (int*)alloc((size_t)E_NUM * T_TOK * 4);
  int* cnt      = (int*)alloc(64);
  int* ndesc    = (int*)alloc(64);
  int4* desc    = (int4*)alloc((size_t)MAX_TILES * 16);

  hipMemsetAsync(cnt, 0, 64, stream);
  hipMemsetAsync(out, 0, (size_t)out_size * 4, stream);

  cast_x_kernel<<<(T_TOK * D_DIM / 4 + 255) / 256, 256, 0, stream>>>(
      x, xb, T_TOK * D_DIM / 4);
  transpose_cast_kernel<<<dim3(F_DIM / 64, D_DIM / 64, E_NUM), 256, 0, stream>>>(
      w1, w1t, D_DIM, F_DIM);  // [D][F] -> [F][D]
  transpose_cast_kernel<<<dim3(D_DIM / 64, F_DIM / 64, E_NUM), 256, 0, stream>>>(
      w2, w2t, F_DIM, D_DIM);  // [F][D] -> [D][F]
  gate_kernel<<<T_TOK / 4, 256, 0, stream>>>(x, gate_w, topk_w, topk_e);
  scatter_kernel<<<2 * T_TOK / 256, 256, 0, stream>>>(topk_e, cnt, assign);
  tiles_kernel<<<1, 64, 0, stream>>>(cnt, ndesc, desc);
  gemm1_kernel<<<dim3(F_DIM / BN, MAX_TILES), 256, 0, stream>>>(
      xb, w1t, b1, assign, ndesc, desc, Hbuf);
  gemm2_kernel<<<dim3(D_DIM / BN, MAX_TILES), 256, 0, stream>>>(
      Hbuf, w2t, b2, assign, topk_w, ndesc, desc, out);
}

// Round 4
// 893.170 us; speedup vs baseline: 1.0285x; 1.0285x over previous
//
#include <hip/hip_runtime.h>

// MoE: T=8192 tokens, D=1024, F=4096, E=8, top-2.
// Pipeline: cast x -> transpose/cast weights to bf16 -> gate -> scatter ->
// grouped GEMM1 (x@w1+b1, gelu) -> H -> grouped GEMM2 (H@w2+b2, *gate_wt,
// atomicAdd into out).
// R3: pipelined K-loop (double LDS buffer, raw s_barrier, fine vmcnt,
// lgkmcnt(0) before the read-done barrier — REQUIRED, DS pipe is unordered
// vs the lds-DMA VMEM pipe).
// R4: occupancy attack. R3 showed 33% occupancy (140 unified regs -> 3
// waves/SIMD) with MfmaUtil 20% and nothing saturated => latency-bound.
// GEMM blocks now 512 thr / 8 waves of 64x32 (acc 32 AGPR, frags 24 VGPR)
// -> target 6 waves/SIMD. Transpose LDS stride 65 + scalar LDS ops (the 68
// stride was 8-way bank-conflicted on both passes).

#define T_TOK 8192
#define D_DIM 1024
#define F_DIM 4096
#define E_NUM 8
#define BM 128
#define BN 128
#define BK 32
#define NK1 (D_DIM / BK)
#define NK2 (F_DIM / BK)
#define MAX_TILES (T_TOK * 2 / BM + E_NUM)  // 136 worst case

typedef float f32x4 __attribute__((ext_vector_type(4)));
typedef short bf16x8 __attribute__((ext_vector_type(8)));

__device__ __forceinline__ unsigned short f2bf(float f) {
  union { float f; unsigned u; } v; v.f = f;
  unsigned r = v.u + 0x7FFFu + ((v.u >> 16) & 1u);  // RNE
  return (unsigned short)(r >> 16);
}

__device__ __forceinline__ void async_cp16(const unsigned short* g, unsigned short* l) {
  // 16B-wide global->LDS DMA. LDS dest is wave-uniform base + lane*16.
  __builtin_amdgcn_global_load_lds((__attribute__((address_space(1))) void*)g,
                                   (__attribute__((address_space(3))) void*)l,
                                   16, 0, 0);
}

#define WAIT_VM2 asm volatile("s_waitcnt vmcnt(2)" ::: "memory")
#define WAIT_LGKM0 asm volatile("s_waitcnt lgkmcnt(0)" ::: "memory")
#define RAW_BARRIER asm volatile("s_barrier" ::: "memory")

// ---------------- small prep kernels ----------------

__global__ void cast_x_kernel(const float* __restrict__ src,
                              unsigned short* __restrict__ dst, int n4) {
  int i = blockIdx.x * blockDim.x + threadIdx.x;
  if (i >= n4) return;
  float4 v = ((const float4*)src)[i];
  ushort4 o;
  o.x = f2bf(v.x); o.y = f2bf(v.y); o.z = f2bf(v.z); o.w = f2bf(v.w);
  ((ushort4*)dst)[i] = o;
}

// src fp32 [R][C] row-major (per expert) -> dst bf16 [C][R].
// float4 global loads, ushort4 global stores. LDS stride 65 floats: both the
// scalar write pass (bank = r+4k+j) and scalar read pass (bank = 4k+j+c) are
// 2-way (free on wave64/32-bank per m136).
__global__ __launch_bounds__(256) void transpose_cast_kernel(
    const float* __restrict__ src, unsigned short* __restrict__ dst,
    int R, int C) {
  __shared__ float tile[64][65];
  int e = blockIdx.z;
  src += (size_t)e * R * C;
  dst += (size_t)e * R * C;
  int c0 = blockIdx.x * 64;
  int r0 = blockIdx.y * 64;
  int t = threadIdx.x;
  int cl = (t & 15) * 4, rl = t >> 4;
#pragma unroll
  for (int i = 0; i < 4; ++i) {
    int r = rl + i * 16;
    float4 v = *(const float4*)(src + (size_t)(r0 + r) * C + c0 + cl);
    tile[r][cl + 0] = v.x;
    tile[r][cl + 1] = v.y;
    tile[r][cl + 2] = v.z;
    tile[r][cl + 3] = v.w;
  }
  __syncthreads();
  int rl2 = (t & 15) * 4, cl2 = t >> 4;
#pragma unroll
  for (int i = 0; i < 4; ++i) {
    int c = cl2 + i * 16;
    ushort4 o;
    o.x = f2bf(tile[rl2 + 0][c]);
    o.y = f2bf(tile[rl2 + 1][c]);
    o.z = f2bf(tile[rl2 + 2][c]);
    o.w = f2bf(tile[rl2 + 3][c]);
    *(ushort4*)(dst + (size_t)(c0 + c) * R + r0 + rl2) = o;
  }
}

// one wave per token: logits = x[t] . gate_w[:,e], fp32; top-2 + softmax
__global__ __launch_bounds__(256) void gate_kernel(
    const float* __restrict__ x, const float* __restrict__ gw,
    float* __restrict__ topk_w, int* __restrict__ topk_e) {
  int t = (blockIdx.x * 256 + threadIdx.x) >> 6;
  int lane = threadIdx.x & 63;
  const float* xr = x + (size_t)t * D_DIM;
  float acc[8];
#pragma unroll
  for (int e = 0; e < 8; ++e) acc[e] = 0.f;
  for (int j = 0; j < D_DIM / 64; ++j) {
    int d = lane + 64 * j;
    float xv = xr[d];
    float4 g0 = ((const float4*)(gw + (size_t)d * 8))[0];
    float4 g1 = ((const float4*)(gw + (size_t)d * 8))[1];
    acc[0] += xv * g0.x; acc[1] += xv * g0.y;
    acc[2] += xv * g0.z; acc[3] += xv * g0.w;
    acc[4] += xv * g1.x; acc[5] += xv * g1.y;
    acc[6] += xv * g1.z; acc[7] += xv * g1.w;
  }
#pragma unroll
  for (int off = 32; off > 0; off >>= 1) {
#pragma unroll
    for (int e = 0; e < 8; ++e) acc[e] += __shfl_xor(acc[e], off);
  }
  if (lane == 0) {
    int e0 = 0; float v0 = acc[0];
#pragma unroll
    for (int e = 1; e < 8; ++e)
      if (acc[e] > v0) { v0 = acc[e]; e0 = e; }  // strict >: lowest index on tie
    int e1 = -1; float v1 = -1e30f;
#pragma unroll
    for (int e = 0; e < 8; ++e)
      if (e != e0 && acc[e] > v1) { v1 = acc[e]; e1 = e; }
    float ex = expf(v1 - v0);
    float inv = 1.f / (1.f + ex);
    topk_w[2 * t] = inv;
    topk_w[2 * t + 1] = ex * inv;
    topk_e[2 * t] = e0;
    topk_e[2 * t + 1] = e1;
  }
}

__global__ void scatter_kernel(const int* __restrict__ topk_e,
                               int* __restrict__ cnt, int* __restrict__ assign) {
  int idx = blockIdx.x * blockDim.x + threadIdx.x;  // (t,k) pair id = t*2+k
  int e = topk_e[idx];
  int pos = atomicAdd(&cnt[e], 1);
  assign[e * T_TOK + pos] = idx;
}

__global__ void tiles_kernel(const int* __restrict__ cnt,
                             int* __restrict__ ndesc, int4* __restrict__ desc) {
  if (threadIdx.x != 0) return;
  int nt = 0, hb = 0;
  for (int e = 0; e < E_NUM; ++e) {
    int c = cnt[e];
    for (int s = 0; s < c; s += BM) {
      int4 d;
      d.x = e; d.y = s; d.z = hb;
      d.w = (c - s < BM) ? (c - s) : BM;
      desc[nt++] = d;
    }
    hb += c;
  }
  *ndesc = nt;
}

// ---------------- grouped GEMMs (pipelined, 8-wave) ----------------
// 128x128 block tile, BK=32, 512 threads = 8 waves of 64x32 (acc[4][2] =
// 32 AGPR -> ~80 unified regs -> 6 waves/SIMD). Per tile each thread issues
// exactly 1 A-chunk + 1 B-chunk DMA (vmcnt(2) waits on the consumed tile,
// next tile's 2 stay in flight). LDS chunk swizzle (rotate 16B chunk by row)
// breaks frag-read conflicts; lds-DMA forbids padding. Step:
//   vmcnt(2) ; barrier ; ds_read frags ; lgkmcnt(0) ; barrier ; issue k+2 ; MFMA

// GEMM1: H[slot][f] = gelu(x[tok] @ w1[e] + b1[e]);  A gathered via assign.
__global__ __launch_bounds__(512, 6) void gemm1_kernel(
    const unsigned short* __restrict__ xb, const unsigned short* __restrict__ w1t,
    const float* __restrict__ b1, const int* __restrict__ assign,
    const int* __restrict__ ndesc, const int4* __restrict__ desc,
    unsigned short* __restrict__ H) {
  int tileid = blockIdx.y;
  if (tileid >= *ndesc) return;
  int4 dc = desc[tileid];
  int e = dc.x, start = dc.y, hbase = dc.z, mcnt = dc.w;
  int n0 = blockIdx.x * BN;  // f-offset

  __shared__ __attribute__((aligned(16))) unsigned short As[2][BM * BK];
  __shared__ __attribute__((aligned(16))) unsigned short Bs[2][BN * BK];

  int tid = threadIdx.x, lane = tid & 63, wv = tid >> 6;

  // chunk id L = tid (512 16B chunks per 8KB tile matrix)
  int row = tid >> 2, cc = tid & 3;
  int g = (cc - row) & 3;            // swizzle: LDS[row][cc] = glob[row][(cc-row)&3]
  int rowc = row < mcnt ? row : (mcnt - 1);
  int a0 = assign[e * T_TOK + start + rowc];
  const unsigned short* gA = xb + (size_t)(a0 >> 1) * D_DIM + g * 8;
  const unsigned short* gB = w1t + (size_t)(e * F_DIM + n0 + row) * D_DIM + g * 8;
  int loff = wv * 512;               // wave-uniform LDS chunk base (shorts)

  int kc16 = lane >> 4, r16 = lane & 15;
  int m_off = (wv & 1) * 64, n_off = (wv >> 1) * 32;
  int aoff[4], boff[2];
#pragma unroll
  for (int i = 0; i < 4; ++i) {
    int ra = m_off + i * 16 + r16;
    aoff[i] = ra * 32 + ((kc16 + ra) & 3) * 8;
  }
#pragma unroll
  for (int j = 0; j < 2; ++j) {
    int rb = n_off + j * 16 + r16;
    boff[j] = rb * 32 + ((kc16 + rb) & 3) * 8;
  }

  f32x4 acc[4][2];
#pragma unroll
  for (int i = 0; i < 4; ++i)
#pragma unroll
    for (int j = 0; j < 2; ++j) acc[i][j] = (f32x4){0.f, 0.f, 0.f, 0.f};

  auto issue = [&](int t, int b) {
    int kc = (t < NK1 ? t : NK1 - 1) * BK;
    async_cp16(gA + kc, &As[b][loff]);
    async_cp16(gB + kc, &Bs[b][loff]);
  };
  auto step = [&](int kt, int b) {
    WAIT_VM2;       // tile kt's 2 DMAs done; tile kt+1's stay in flight
    RAW_BARRIER;    // all waves have tile kt in LDS
    bf16x8 af[4], bfr[2];
#pragma unroll
    for (int i = 0; i < 4; ++i) af[i] = *(const bf16x8*)(&As[b][0] + aoff[i]);
#pragma unroll
    for (int j = 0; j < 2; ++j) bfr[j] = *(const bf16x8*)(&Bs[b][0] + boff[j]);
    WAIT_LGKM0;     // DS queue drained: frags in registers
    RAW_BARRIER;    // all waves done reading buffer b -> safe to overwrite
    issue(kt + 2, b);
#pragma unroll
    for (int i = 0; i < 4; ++i)
#pragma unroll
      for (int j = 0; j < 2; ++j)
        acc[i][j] = __builtin_amdgcn_mfma_f32_16x16x32_bf16(af[i], bfr[j], acc[i][j], 0, 0, 0);
  };

  issue(0, 0);
  issue(1, 1);
  for (int kt = 0; kt < NK1; kt += 2) { step(kt, 0); step(kt + 1, 1); }

  // epilogue: C/D layout col=lane&15, row=(lane>>4)*4+reg
  int col = lane & 15, rbase = (lane >> 4) * 4;
  float bias[2];
#pragma unroll
  for (int j = 0; j < 2; ++j) bias[j] = b1[e * F_DIM + n0 + n_off + j * 16 + col];
#pragma unroll
  for (int i = 0; i < 4; ++i) {
#pragma unroll
    for (int rg = 0; rg < 4; ++rg) {
      int r = m_off + i * 16 + rbase + rg;
      if (r < mcnt) {
        unsigned short* hrow = H + (size_t)(hbase + start + r) * F_DIM + n0 + n_off + col;
#pragma unroll
        for (int j = 0; j < 2; ++j) {
          float v = acc[i][j][rg] + bias[j];
          v = 0.5f * v * (1.0f + erff(v * 0.70710678118654752f));  // exact gelu
          hrow[j * 16] = f2bf(v);
        }
      }
    }
  }
}

// GEMM2: out[tok] += wt * (H[slot] @ w2[e] + b2[e])
__global__ __launch_bounds__(512, 6) void gemm2_kernel(
    const unsigned short* __restrict__ H, const unsigned short* __restrict__ w2t,
    const float* __restrict__ b2, const int* __restrict__ assign,
    const float* __restrict__ topk_w,
    const int* __restrict__ ndesc, const int4* __restrict__ desc,
    float* __restrict__ out) {
  int tileid = blockIdx.y;
  if (tileid >= *ndesc) return;
  int4 dc = desc[tileid];
  int e = dc.x, start = dc.y, hbase = dc.z, mcnt = dc.w;
  int n0 = blockIdx.x * BN;  // d-offset

  __shared__ __attribute__((aligned(16))) unsigned short As[2][BM * BK];
  __shared__ __attribute__((aligned(16))) unsigned short Bs[2][BN * BK];

  int tid = threadIdx.x, lane = tid & 63, wv = tid >> 6;

  int row = tid >> 2, cc = tid & 3;
  int g = (cc - row) & 3;
  int rowc = row < mcnt ? row : (mcnt - 1);
  const unsigned short* gA = H + (size_t)(hbase + start + rowc) * F_DIM + g * 8;
  const unsigned short* gB = w2t + (size_t)(e * D_DIM + n0 + row) * F_DIM + g * 8;
  int loff = wv * 512;

  int kc16 = lane >> 4, r16 = lane & 15;
  int m_off = (wv & 1) * 64, n_off = (wv >> 1) * 32;
  int aoff[4], boff[2];
#pragma unroll
  for (int i = 0; i < 4; ++i) {
    int ra = m_off + i * 16 + r16;
    aoff[i] = ra * 32 + ((kc16 + ra) & 3) * 8;
  }
#pragma unroll
  for (int j = 0; j < 2; ++j) {
    int rb = n_off + j * 16 + r16;
    boff[j] = rb * 32 + ((kc16 + rb) & 3) * 8;
  }

  f32x4 acc[4][2];
#pragma unroll
  for (int i = 0; i < 4; ++i)
#pragma unroll
    for (int j = 0; j < 2; ++j) acc[i][j] = (f32x4){0.f, 0.f, 0.f, 0.f};

  auto issue = [&](int t, int b) {
    int kc = (t < NK2 ? t : NK2 - 1) * BK;
    async_cp16(gA + kc, &As[b][loff]);
    async_cp16(gB + kc, &Bs[b][loff]);
  };
  auto step = [&](int kt, int b) {
    WAIT_VM2;
    RAW_BARRIER;
    bf16x8 af[4], bfr[2];
#pragma unroll
    for (int i = 0; i < 4; ++i) af[i] = *(const bf16x8*)(&As[b][0] + aoff[i]);
#pragma unroll
    for (int j = 0; j < 2; ++j) bfr[j] = *(const bf16x8*)(&Bs[b][0] + boff[j]);
    WAIT_LGKM0;
    RAW_BARRIER;
    issue(kt + 2, b);
#pragma unroll
    for (int i = 0; i < 4; ++i)
#pragma unroll
      for (int j = 0; j < 2; ++j)
        acc[i][j] = __builtin_amdgcn_mfma_f32_16x16x32_bf16(af[i], bfr[j], acc[i][j], 0, 0, 0);
  };

  issue(0, 0);
  issue(1, 1);
  for (int kt = 0; kt < NK2; kt += 2) { step(kt, 0); step(kt + 1, 1); }

  int col = lane & 15, rbase = (lane >> 4) * 4;
  float bias[2];
#pragma unroll
  for (int j = 0; j < 2; ++j) bias[j] = b2[e * D_DIM + n0 + n_off + j * 16 + col];
#pragma unroll
  for (int i = 0; i < 4; ++i) {
#pragma unroll
    for (int rg = 0; rg < 4; ++rg) {
      int r = m_off + i * 16 + rbase + rg;
      if (r < mcnt) {
        int a = assign[e * T_TOK + start + r];
        float wt = topk_w[a];
        float* orow = out + (size_t)(a >> 1) * D_DIM + n0 + n_off + col;
#pragma unroll
        for (int j = 0; j < 2; ++j) {
          float v = acc[i][j][rg] + bias[j];
          atomicAdd(orow + j * 16, wt * v);  // 2 contenders/address
        }
      }
    }
  }
}

// ---------------- launcher ----------------

extern "C" void kernel_launch(void* const* d_in, const int* in_sizes, int n_in,
                              void* d_out, int out_size, void* d_ws, size_t ws_size,
                              hipStream_t stream) {
  const float* x      = (const float*)d_in[0];
  const float* gate_w = (const float*)d_in[1];
  const float* w1     = (const float*)d_in[2];
  const float* b1     = (const float*)d_in[3];
  const float* w2     = (const float*)d_in[4];
  const float* b2     = (const float*)d_in[5];
  float* out = (float*)d_out;

  char* ws = (char*)d_ws;
  size_t off = 0;
  auto alloc = [&](size_t bytes) {
    char* p = ws + off;
    off = (off + bytes + 255) & ~(size_t)255;
    return p;
  };
  unsigned short* xb   = (unsigned short*)alloc((size_t)T_TOK * D_DIM * 2);
  unsigned short* w1t  = (unsigned short*)alloc((size_t)E_NUM * D_DIM * F_DIM * 2);
  unsigned short* w2t  = (unsigned short*)alloc((size_t)E_NUM * D_DIM * F_DIM * 2);
  unsigned short* Hbuf = (unsigned short*)alloc((size_t)2 * T_TOK * F_DIM * 2);
  float* topk_w = (float*)alloc((size_t)2 * T_TOK * 4);
  int* topk_e   = (int*)alloc((size_t)2 * T_TOK * 4);
  int* assign   = (int*)alloc((size_t)E_NUM * T_TOK * 4);
  int* cnt      = (int*)alloc(64);
  int* ndesc    = (int*)alloc(64);
  int4* desc    = (int4*)alloc((size_t)MAX_TILES * 16);

  hipMemsetAsync(cnt, 0, 64, stream);
  hipMemsetAsync(out, 0, (size_t)out_size * 4, stream);

  cast_x_kernel<<<(T_TOK * D_DIM / 4 + 255) / 256, 256, 0, stream>>>(
      x, xb, T_TOK * D_DIM / 4);
  transpose_cast_kernel<<<dim3(F_DIM / 64, D_DIM / 64, E_NUM), 256, 0, stream>>>(
      w1, w1t, D_DIM, F_DIM);  // [D][F] -> [F][D]
  transpose_cast_kernel<<<dim3(D_DIM / 64, F_DIM / 64, E_NUM), 256, 0, stream>>>(
      w2, w2t, F_DIM, D_DIM);  // [F][D] -> [D][F]
  gate_kernel<<<T_TOK / 4, 256, 0, stream>>>(x, gate_w, topk_w, topk_e);
  scatter_kernel<<<2 * T_TOK / 256, 256, 0, stream>>>(topk_e, cnt, assign);
  tiles_kernel<<<1, 64, 0, stream>>>(cnt, ndesc, desc);
  gemm1_kernel<<<dim3(F_DIM / BN, MAX_TILES), 512, 0, stream>>>(
      xb, w1t, b1, assign, ndesc, desc, Hbuf);
  gemm2_kernel<<<dim3(D_DIM / BN, MAX_TILES), 512, 0, stream>>>(
      Hbuf, w2t, b2, assign, topk_w, ndesc, desc, out);
}